// Round 8
// baseline (279.348 us; speedup 1.0000x reference)
//
#include <hip/hip_runtime.h>
#include <math.h>

// Problem constants
#define BB 512
#define VV 2
#define MM 1024
#define DD 128
#define KMAX 50
#define TOPK 15
#define INV_T (1.0f/0.07f)

// In-kernel idempotent repetition for per-kernel rocprof attribution.
// True dur = reported dur / REPS_*. All stores rewrite identical values.
#define REPS_K0 64
#define REPS_K1 32
#define REPS_K2 32
#define REPS_K3 64

// ---------------- Workspace layout (byte offsets) ----------------
#define OFF_ANCH  0                      // bf16 [MM][DD]   256 KB
#define OFF_A2    262144                 // f32  [MM]         4 KB
#define OFF_ACCT  266240                 // f32  [BB][MM]     2 MB : accT[b][i] = acc(i,b)
#define OFF_PART  (266240 + 2097152)     // f32  [16][MM]    64 KB : per-jg partial expsums
#define OFF_LSPOS (OFF_PART + 65536)     // f32  [MM]         4 KB

typedef __attribute__((ext_vector_type(8))) short bf16x8;
typedef __attribute__((ext_vector_type(4))) float f32x4;

// f32 -> bf16 (RNE)
__device__ __forceinline__ short f2bf(float x)
{
    union { float f; unsigned u; } a; a.f = x;
    return (short)((a.u + 0x7FFFu + ((a.u >> 16) & 1u)) >> 16);
}

// convert 8 f32 (two float4) to bf16x8, accumulating sum of squares
__device__ __forceinline__ bf16x8 cvt8(float4 p0, float4 p1, float& nacc)
{
    float v[8] = {p0.x, p0.y, p0.z, p0.w, p1.x, p1.y, p1.z, p1.w};
    bf16x8 r;
    #pragma unroll
    for (int e = 0; e < 8; ++e) {
        nacc = fmaf(v[e], v[e], nacc);
        r[e] = f2bf(v[e]);
    }
    return r;
}

// ---------------------------------------------------------------------------
// K0: anchor (transposed features) -> bf16 + exact f32 norms.
// ---------------------------------------------------------------------------
__global__ __launch_bounds__(256) void k0_anchor(
    const float* __restrict__ feat,
    unsigned* __restrict__ anchor_u,
    float* __restrict__ a2)
{
    #pragma unroll 1
    for (int rep = 0; rep < REPS_K0; ++rep) {
        const int row  = blockIdx.x * 4 + (threadIdx.x >> 6);
        const int lane = threadIdx.x & 63;
        const int frow = (row & (BB - 1)) * VV + (row >> 9);
        float2 v = *(const float2*)&feat[(size_t)frow * DD + lane * 2];
        unsigned lo = (unsigned)(unsigned short)f2bf(v.x);
        unsigned hi = (unsigned)(unsigned short)f2bf(v.y);
        anchor_u[row * (DD / 2) + lane] = lo | (hi << 16);
        float sq = v.x * v.x + v.y * v.y;
        #pragma unroll
        for (int off = 32; off > 0; off >>= 1) sq += __shfl_xor(sq, off);
        if (lane == 0) a2[row] = sq;
    }
}

// ---------------------------------------------------------------------------
// K1: neighbor MFMA GEMM -> accT[b][i].  (exact R6 structure, grid (128,4))
// ---------------------------------------------------------------------------
__global__ __launch_bounds__(256) void k1_acc(
    const short* __restrict__ anchor,
    const float* __restrict__ a2,
    const int* __restrict__ indices,
    const float* __restrict__ saved, const int* __restrict__ rks,
    float* __restrict__ accT)
{
    #pragma unroll 1
    for (int rep = 0; rep < REPS_K1; ++rep) {
        const int tid = threadIdx.x;
        const int lane = tid & 63;
        const int wid = tid >> 6;
        const int lr = lane & 15;
        const int lg = lane >> 4;
        const int wr = wid >> 1;
        const int wc = wid & 1;
        const int m0 = blockIdx.x * 64 + wr * 32;

        int aidx[2];
        #pragma unroll
        for (int tm = 0; tm < 2; ++tm) {
            int b = (m0 >> 4) + tm;
            aidx[tm] = rks[(size_t)indices[b] * KMAX + lr];
        }
        bf16x8 af[2][4];
        float nnA[2] = {0.f, 0.f};
        #pragma unroll
        for (int tm = 0; tm < 2; ++tm)
            #pragma unroll
            for (int kc = 0; kc < 4; ++kc) {
                const float4* p = (const float4*)&saved[(size_t)aidx[tm] * DD + kc * 32 + lg * 8];
                af[tm][kc] = cvt8(p[0], p[1], nnA[tm]);
            }
        #pragma unroll
        for (int tm = 0; tm < 2; ++tm) {
            nnA[tm] += __shfl_xor(nnA[tm], 16);
            nnA[tm] += __shfl_xor(nnA[tm], 32);
        }
        float nnAr[2][4];
        #pragma unroll
        for (int tm = 0; tm < 2; ++tm)
            #pragma unroll
            for (int r = 0; r < 4; ++r)
                nnAr[tm][r] = __shfl(nnA[tm], lg * 4 + r);

        #pragma unroll
        for (int jt = 0; jt < 2; ++jt) {
            const int j0 = blockIdx.y * 256 + jt * 128 + wc * 64;
            f32x4 acc[2][4];
            #pragma unroll
            for (int a = 0; a < 2; ++a)
                #pragma unroll
                for (int b = 0; b < 4; ++b) acc[a][b] = (f32x4){0.f, 0.f, 0.f, 0.f};
            #pragma unroll
            for (int kc = 0; kc < 4; ++kc) {
                bf16x8 bf[4];
                #pragma unroll
                for (int tn = 0; tn < 4; ++tn)
                    bf[tn] = *(const bf16x8*)&anchor[(size_t)(j0 + tn * 16 + lr) * DD + kc * 32 + lg * 8];
                #pragma unroll
                for (int tm = 0; tm < 2; ++tm)
                    #pragma unroll
                    for (int tn = 0; tn < 4; ++tn)
                        acc[tm][tn] = __builtin_amdgcn_mfma_f32_16x16x32_bf16(
                            af[tm][kc], bf[tn], acc[tm][tn], 0, 0, 0);
            }
            #pragma unroll
            for (int tm = 0; tm < 2; ++tm) {
                const int b = (m0 >> 4) + tm;
                #pragma unroll
                for (int tn = 0; tn < 4; ++tn) {
                    const float a2j = a2[j0 + tn * 16 + lr];
                    float s = 0.f;
                    #pragma unroll
                    for (int r = 0; r < 4; ++r) {
                        float g = acc[tm][tn][r];
                        float sq = fmaxf(fmaf(-2.f, g, a2j + nnAr[tm][r]), 0.f);
                        float d = __builtin_amdgcn_sqrtf(sq);
                        float f = fmaf(__builtin_amdgcn_rcpf(1.f + d), INV_T, INV_T);
                        if (lg == 3 && r == 3) f = 0.f;
                        s += f;
                    }
                    s += __shfl_xor(s, 16);
                    s += __shfl_xor(s, 32);
                    if (lane < 16)
                        accT[(size_t)b * MM + j0 + tn * 16 + lane] = s * (1.0f / TOPK);
                }
            }
        }
    }
}

// ---------------------------------------------------------------------------
// K2: S-tile MFMA + adc + ls + exp partial sums.  (exact R6 structure)
// ---------------------------------------------------------------------------
__global__ __launch_bounds__(256) void k2_exp(
    const short* __restrict__ anchor, const float* __restrict__ a2,
    const float* __restrict__ accT,
    float* __restrict__ part, float* __restrict__ lspos)
{
    __shared__ float pshare[4][16];
    #pragma unroll 1
    for (int rep = 0; rep < REPS_K2; ++rep) {
        const int tid = threadIdx.x;
        const int lane = tid & 63;
        const int wid = tid >> 6;
        const int lr = lane & 15;
        const int lg = lane >> 4;
        const int i0 = blockIdx.x * 16;
        const int jg = blockIdx.y;
        const int jcol = jg * 64 + wid * 16 + lr;

        f32x4 acc = (f32x4){0.f, 0.f, 0.f, 0.f};
        #pragma unroll
        for (int kc = 0; kc < 4; ++kc) {
            bf16x8 af = *(const bf16x8*)&anchor[(size_t)(i0 + lr) * DD + kc * 32 + lg * 8];
            bf16x8 bf = *(const bf16x8*)&anchor[(size_t)jcol * DD + kc * 32 + lg * 8];
            acc = __builtin_amdgcn_mfma_f32_16x16x32_bf16(af, bf, acc, 0, 0, 0);
        }
        const int ib4 = i0 + lg * 4;
        const float4 a2i4 = *(const float4*)&a2[ib4];
        const float a2iv[4] = {a2i4.x, a2i4.y, a2i4.z, a2i4.w};
        const float a2j = a2[jcol];
        const float4 aij4 = *(const float4*)&accT[(size_t)(jcol & (BB - 1)) * MM + ib4];
        const float aijv[4] = {aij4.x, aij4.y, aij4.z, aij4.w};

        float esum[4];
        #pragma unroll
        for (int r = 0; r < 4; ++r) {
            const int i = ib4 + r;
            float g = acc[r];
            float sq = fmaxf(fmaf(-2.f, g, a2iv[r] + a2j), 0.f);
            float d0 = __builtin_amdgcn_sqrtf(sq);
            float adc = fmaf(__builtin_amdgcn_rcpf(1.f + d0), INV_T, INV_T);
            float aji = accT[(size_t)(i & (BB - 1)) * MM + jcol];
            float ls = __builtin_amdgcn_sqrtf(aijv[r] * aijv[r] + aji * aji + adc * adc);
            esum[r] = (jcol == i) ? 0.f : __expf(ls);
            if (jcol == (i ^ BB)) lspos[i] = ls;
        }
        #pragma unroll
        for (int r = 0; r < 4; ++r) {
            float e = esum[r];
            e += __shfl_xor(e, 1);
            e += __shfl_xor(e, 2);
            e += __shfl_xor(e, 4);
            e += __shfl_xor(e, 8);
            if (lr == 0) pshare[wid][lg * 4 + r] = e;
        }
        __syncthreads();
        if (tid < 16)
            part[jg * MM + i0 + tid] =
                pshare[0][tid] + pshare[1][tid] + pshare[2][tid] + pshare[3][tid];
        __syncthreads();
    }
}

// ---------------------------------------------------------------------------
// K3: finish — loss per row + mean, single block.  (exact R6 structure)
// ---------------------------------------------------------------------------
__global__ __launch_bounds__(256) void k3_finish(
    const float* __restrict__ part, const float* __restrict__ lspos,
    float* __restrict__ out)
{
    __shared__ float red[4];
    #pragma unroll 1
    for (int rep = 0; rep < REPS_K3; ++rep) {
        const int tid = threadIdx.x;
        const int lane = tid & 63, w = tid >> 6;
        float lsum = 0.f;
        #pragma unroll
        for (int q = 0; q < 4; ++q) {
            const int i = tid + q * 256;
            float s = 0.f;
            #pragma unroll
            for (int jg = 0; jg < 16; ++jg) s += part[jg * MM + i];
            lsum += __logf(s) - lspos[i];
        }
        #pragma unroll
        for (int off = 32; off > 0; off >>= 1) lsum += __shfl_xor(lsum, off);
        if (lane == 0) red[w] = lsum;
        __syncthreads();
        if (tid == 0) out[0] = (red[0] + red[1] + red[2] + red[3]) * (1.0f / MM);
        __syncthreads();
    }
}

// ---------------------------------------------------------------------------
extern "C" void kernel_launch(void* const* d_in, const int* in_sizes, int n_in,
                              void* d_out, int out_size, void* d_ws, size_t ws_size,
                              hipStream_t stream)
{
    const float* feat    = (const float*)d_in[0];  // (512, 2, 128) f32
    const int*   indices = (const int*)  d_in[1];  // (512,) i32
    const float* saved   = (const float*)d_in[2];  // (100000, 128) f32
    const int*   rks     = (const int*)  d_in[3];  // (100000, 50) i32

    char* w = (char*)d_ws;
    short* anchor = (short*)(w + OFF_ANCH);
    float* a2     = (float*)(w + OFF_A2);
    float* accT   = (float*)(w + OFF_ACCT);
    float* part   = (float*)(w + OFF_PART);
    float* lspos  = (float*)(w + OFF_LSPOS);

    k0_anchor<<<MM / 4, 256, 0, stream>>>(feat, (unsigned*)anchor, a2);
    k1_acc<<<dim3(128, 4), 256, 0, stream>>>(anchor, a2, indices, saved, rks, accT);
    k2_exp<<<dim3(64, 16), 256, 0, stream>>>(anchor, a2, accT, part, lspos);
    k3_finish<<<1, 256, 0, stream>>>(part, lspos, (float*)d_out);
}

// Round 9
// 56.417 us; speedup vs baseline: 4.9515x; 4.9515x over previous
//
#include <hip/hip_runtime.h>
#include <math.h>

// Problem constants
#define BB 512
#define VV 2
#define MM 1024
#define DD 128
#define KMAX 50
#define TOPK 15
#define INV_T (1.0f/0.07f)

// ---------------- Workspace layout (byte offsets) ----------------
#define OFF_ACCT  0                      // f32 [BB][MM]  2 MB : accT[b][i] = acc(i,b)
#define OFF_BPART (2*1024*1024)          // f32 [64]           : per-block loss partials
#define OFF_CNT   (OFF_BPART + 256)      // u32 [1]            : finished-block counter

typedef __attribute__((ext_vector_type(8))) short bf16x8;
typedef __attribute__((ext_vector_type(4))) float f32x4;

// f32 -> bf16 (RNE)
__device__ __forceinline__ short f2bf(float x)
{
    union { float f; unsigned u; } a; a.f = x;
    return (short)((a.u + 0x7FFFu + ((a.u >> 16) & 1u)) >> 16);
}

// convert 8 f32 (two float4) to bf16x8, accumulating sum of squares
__device__ __forceinline__ bf16x8 cvt8(float4 p0, float4 p1, float& nacc)
{
    float v[8] = {p0.x, p0.y, p0.z, p0.w, p1.x, p1.y, p1.z, p1.w};
    bf16x8 r;
    #pragma unroll
    for (int e = 0; e < 8; ++e) {
        nacc = fmaf(v[e], v[e], nacc);
        r[e] = f2bf(v[e]);
    }
    return r;
}

// anchor row/col j lives at feat[((j&511)*2 + (j>>9)) * 128 + d]
__device__ __forceinline__ const float4* feat_ptr(const float* feat, int j, int d)
{
    int frow = (j & (BB - 1)) * VV + (j >> 9);
    return (const float4*)&feat[(size_t)frow * DD + d];
}

// ---------------------------------------------------------------------------
// K1: neighbor MFMA GEMM -> accT[b][i].  Grid (128,4), 256 thr = 4 waves 2x2.
// Reads saved (gather) AND feat directly; f32->bf16 in-register; exact f32
// norms via lane-class shfl_xor reduce (lane l holds norm of row/col (l&15)).
// Also zeroes the K2 completion counter (ws is poisoned to 0xAA).
// C layout (mfma_f32_16x16x32_bf16): col = lane&15, row(k) = (lane>>4)*4 + reg.
// ---------------------------------------------------------------------------
__global__ __launch_bounds__(256) void k1_acc(
    const float* __restrict__ feat, const int* __restrict__ indices,
    const float* __restrict__ saved, const int* __restrict__ rks,
    float* __restrict__ accT, unsigned* __restrict__ cnt)
{
    if (blockIdx.x == 0 && blockIdx.y == 0 && threadIdx.x == 0) *cnt = 0u;

    const int tid = threadIdx.x;
    const int lane = tid & 63;
    const int wid = tid >> 6;
    const int lr = lane & 15;
    const int lg = lane >> 4;
    const int wr = wid >> 1;
    const int wc = wid & 1;
    const int m0 = blockIdx.x * 64 + wr * 32;        // neighbor row base

    // A side: gather 2 b-groups' saved rows (k = lr; k=15 masked in epilogue)
    int aidx[2];
    #pragma unroll
    for (int tm = 0; tm < 2; ++tm) {
        int b = (m0 >> 4) + tm;
        aidx[tm] = rks[(size_t)indices[b] * KMAX + lr];
    }
    bf16x8 af[2][4];
    float nnA[2] = {0.f, 0.f};
    #pragma unroll
    for (int tm = 0; tm < 2; ++tm)
        #pragma unroll
        for (int kc = 0; kc < 4; ++kc) {
            const float4* p = (const float4*)&saved[(size_t)aidx[tm] * DD + kc * 32 + lg * 8];
            af[tm][kc] = cvt8(p[0], p[1], nnA[tm]);
        }
    #pragma unroll
    for (int tm = 0; tm < 2; ++tm) {
        nnA[tm] += __shfl_xor(nnA[tm], 16);
        nnA[tm] += __shfl_xor(nnA[tm], 32);          // lane: full norm of row lr
    }
    float nnAr[2][4];
    #pragma unroll
    for (int tm = 0; tm < 2; ++tm)
        #pragma unroll
        for (int r = 0; r < 4; ++r)
            nnAr[tm][r] = __shfl(nnA[tm], lg * 4 + r);   // norm of C-row lg*4+r

    #pragma unroll
    for (int jt = 0; jt < 2; ++jt) {
        const int j0 = blockIdx.y * 256 + jt * 128 + wc * 64;
        f32x4 acc[2][4];
        #pragma unroll
        for (int a = 0; a < 2; ++a)
            #pragma unroll
            for (int b = 0; b < 4; ++b) acc[a][b] = (f32x4){0.f, 0.f, 0.f, 0.f};
        float nnB[4] = {0.f, 0.f, 0.f, 0.f};
        #pragma unroll
        for (int kc = 0; kc < 4; ++kc) {
            bf16x8 bf[4];
            #pragma unroll
            for (int tn = 0; tn < 4; ++tn) {
                const float4* p = feat_ptr(feat, j0 + tn * 16 + lr, kc * 32 + lg * 8);
                bf[tn] = cvt8(p[0], p[1], nnB[tn]);
            }
            #pragma unroll
            for (int tm = 0; tm < 2; ++tm)
                #pragma unroll
                for (int tn = 0; tn < 4; ++tn)
                    acc[tm][tn] = __builtin_amdgcn_mfma_f32_16x16x32_bf16(
                        af[tm][kc], bf[tn], acc[tm][tn], 0, 0, 0);
        }
        #pragma unroll
        for (int tn = 0; tn < 4; ++tn) {
            nnB[tn] += __shfl_xor(nnB[tn], 16);
            nnB[tn] += __shfl_xor(nnB[tn], 32);      // lane: full norm of col lr
        }
        #pragma unroll
        for (int tm = 0; tm < 2; ++tm) {
            const int b = (m0 >> 4) + tm;
            #pragma unroll
            for (int tn = 0; tn < 4; ++tn) {
                const float a2j = nnB[tn];
                float s = 0.f;
                #pragma unroll
                for (int r = 0; r < 4; ++r) {
                    float g = acc[tm][tn][r];
                    float sq = fmaxf(fmaf(-2.f, g, a2j + nnAr[tm][r]), 0.f);
                    float d = __builtin_amdgcn_sqrtf(sq);
                    float f = fmaf(__builtin_amdgcn_rcpf(1.f + d), INV_T, INV_T);
                    if (lg == 3 && r == 3) f = 0.f;  // k == 15 pad row
                    s += f;
                }
                s += __shfl_xor(s, 16);
                s += __shfl_xor(s, 32);              // sum the 16 k-rows
                if (lane < 16)
                    accT[(size_t)b * MM + j0 + tn * 16 + lane] = s * (1.0f / TOPK);
            }
        }
    }
}

// ---------------------------------------------------------------------------
// K2: fused S-GEMM + adc + ls + exp + per-row loss + mean.
// Grid 64 blocks x 1024 thr (16 waves). Block owns rows i0..i0+15 and ALL
// 1024 cols (wave w handles col group jg = w). rowsum/lspos complete
// in-block; one fenced atomic per block; 64th block reduces 64 partials.
// (No max subtraction: ls in [24.7, 49.5]; verified rounds 4-8, absmax 0.)
// ---------------------------------------------------------------------------
__global__ __launch_bounds__(1024) void k2_loss(
    const float* __restrict__ feat, const float* __restrict__ accT,
    float* __restrict__ bpart, unsigned* __restrict__ cnt,
    float* __restrict__ out)
{
    __shared__ float pshare[16][16];   // [wave][row] partial expsums
    __shared__ float lspos16[16];
    __shared__ int iswin;
    const int tid = threadIdx.x;
    const int lane = tid & 63;
    const int wid = tid >> 6;          // = jg, 0..15
    const int lr = lane & 15;
    const int lg = lane >> 4;
    const int i0 = blockIdx.x * 16;
    const int ib4 = i0 + lg * 4;

    // A fragments + exact row norms
    bf16x8 af[4];
    float pA = 0.f;
    #pragma unroll
    for (int kc = 0; kc < 4; ++kc) {
        const float4* p = feat_ptr(feat, i0 + lr, kc * 32 + lg * 8);
        af[kc] = cvt8(p[0], p[1], pA);
    }
    pA += __shfl_xor(pA, 16);
    pA += __shfl_xor(pA, 32);
    float a2iv[4];
    #pragma unroll
    for (int r = 0; r < 4; ++r) a2iv[r] = __shfl(pA, lg * 4 + r);

    // B tiles (4 x 16 cols) + MFMA + col norms
    f32x4 acc[4];
    #pragma unroll
    for (int t = 0; t < 4; ++t) acc[t] = (f32x4){0.f, 0.f, 0.f, 0.f};
    float nnB[4] = {0.f, 0.f, 0.f, 0.f};
    #pragma unroll
    for (int kc = 0; kc < 4; ++kc) {
        #pragma unroll
        for (int tn = 0; tn < 4; ++tn) {
            const float4* p = feat_ptr(feat, wid * 64 + tn * 16 + lr, kc * 32 + lg * 8);
            bf16x8 bf = cvt8(p[0], p[1], nnB[tn]);
            acc[tn] = __builtin_amdgcn_mfma_f32_16x16x32_bf16(af[kc], bf, acc[tn], 0, 0, 0);
        }
    }
    #pragma unroll
    for (int tn = 0; tn < 4; ++tn) {
        nnB[tn] += __shfl_xor(nnB[tn], 16);
        nnB[tn] += __shfl_xor(nnB[tn], 32);
    }

    // epilogue: adc, ls, exp; accumulate over this wave's 64 cols
    float es[4] = {0.f, 0.f, 0.f, 0.f};
    #pragma unroll
    for (int tn = 0; tn < 4; ++tn) {
        const int jcol = wid * 64 + tn * 16 + lr;
        const float a2j = nnB[tn];
        const float4 aij4 = *(const float4*)&accT[(size_t)(jcol & (BB - 1)) * MM + ib4];
        const float aijv[4] = {aij4.x, aij4.y, aij4.z, aij4.w};
        #pragma unroll
        for (int r = 0; r < 4; ++r) {
            const int i = ib4 + r;
            float g = acc[tn][r];
            float sq = fmaxf(fmaf(-2.f, g, a2iv[r] + a2j), 0.f);
            float d0 = __builtin_amdgcn_sqrtf(sq);
            float adc = fmaf(__builtin_amdgcn_rcpf(1.f + d0), INV_T, INV_T);
            float aji = accT[(size_t)(i & (BB - 1)) * MM + jcol];
            float ls = __builtin_amdgcn_sqrtf(aijv[r] * aijv[r] + aji * aji + adc * adc);
            es[r] += (jcol == i) ? 0.f : __expf(ls);
            if (jcol == (i ^ BB)) lspos16[i - i0] = ls;   // the positive pair
        }
    }
    #pragma unroll
    for (int r = 0; r < 4; ++r) {
        float e = es[r];
        e += __shfl_xor(e, 1);
        e += __shfl_xor(e, 2);
        e += __shfl_xor(e, 4);
        e += __shfl_xor(e, 8);                       // sum 16 lr-lanes
        if (lr == 0) pshare[wid][lg * 4 + r] = e;
    }
    __syncthreads();

    // per-row loss + block partial (wave 0 only)
    if (wid == 0) {
        float v = 0.f;
        if (lane < 16) {
            float s = 0.f;
            #pragma unroll
            for (int w = 0; w < 16; ++w) s += pshare[w][lane];
            v = __logf(s) - lspos16[lane];
        }
        #pragma unroll
        for (int off = 32; off > 0; off >>= 1) v += __shfl_xor(v, off);
        if (lane == 0) {
            bpart[blockIdx.x] = v;
            __threadfence();
            unsigned old = atomicAdd(cnt, 1u);
            iswin = (old == 63u);
        }
    }
    __syncthreads();
    if (!iswin) return;

    // last block: final mean over the 64 block partials
    __threadfence();
    if (wid == 0) {
        float v = bpart[lane];                       // 64 blocks, 64 lanes
        #pragma unroll
        for (int off = 32; off > 0; off >>= 1) v += __shfl_xor(v, off);
        if (lane == 0) out[0] = v * (1.0f / MM);
    }
}

// ---------------------------------------------------------------------------
extern "C" void kernel_launch(void* const* d_in, const int* in_sizes, int n_in,
                              void* d_out, int out_size, void* d_ws, size_t ws_size,
                              hipStream_t stream)
{
    const float* feat    = (const float*)d_in[0];  // (512, 2, 128) f32
    const int*   indices = (const int*)  d_in[1];  // (512,) i32
    const float* saved   = (const float*)d_in[2];  // (100000, 128) f32
    const int*   rks     = (const int*)  d_in[3];  // (100000, 50) i32

    char* w = (char*)d_ws;
    float*    accT  = (float*)   (w + OFF_ACCT);
    float*    bpart = (float*)   (w + OFF_BPART);
    unsigned* cnt   = (unsigned*)(w + OFF_CNT);

    // K1: neighbor GEMM -> accT (direct reads, in-register cvt+norms); cnt=0
    k1_acc<<<dim3(128, 4), 256, 0, stream>>>(feat, indices, saved, rks, accT, cnt);
    // K2: fused S-GEMM + exp + loss + mean (last block writes out)
    k2_loss<<<64, 1024, 0, stream>>>(feat, accT, bpart, cnt, (float*)d_out);
}

// Round 10
// 36.977 us; speedup vs baseline: 7.5547x; 1.5257x over previous
//
#include <hip/hip_runtime.h>
#include <math.h>

// Problem constants
#define BB 512
#define VV 2
#define MM 1024
#define DD 128
#define KMAX 50
#define TOPK 15
#define INV_T (1.0f/0.07f)

// ---------------- Workspace layout (byte offsets) ----------------
#define OFF_ANCH  0                      // bf16 [MM][DD]   256 KB
#define OFF_A2    262144                 // f32  [MM]         4 KB
#define OFF_ACCT  266240                 // f32  [BB][MM]     2 MB : accT[b][i] = acc(i,b)
#define OFF_PART  (266240 + 2097152)     // f32  [16][MM]    64 KB : per-jg partial expsums
#define OFF_LSPOS (OFF_PART + 65536)     // f32  [MM]         4 KB

typedef __attribute__((ext_vector_type(8))) short bf16x8;
typedef __attribute__((ext_vector_type(4))) float f32x4;

// f32 -> bf16 (RNE)
__device__ __forceinline__ short f2bf(float x)
{
    union { float f; unsigned u; } a; a.f = x;
    return (short)((a.u + 0x7FFFu + ((a.u >> 16) & 1u)) >> 16);
}

// convert 8 f32 (two float4) to bf16x8, accumulating sum of squares
__device__ __forceinline__ bf16x8 cvt8(float4 p0, float4 p1, float& nacc)
{
    float v[8] = {p0.x, p0.y, p0.z, p0.w, p1.x, p1.y, p1.z, p1.w};
    bf16x8 r;
    #pragma unroll
    for (int e = 0; e < 8; ++e) {
        nacc = fmaf(v[e], v[e], nacc);
        r[e] = f2bf(v[e]);
    }
    return r;
}

// anchor row/col j lives at feat[((j&511)*2 + (j>>9)) * 128 + d]
__device__ __forceinline__ const float4* feat_ptr(const float* feat, int j, int d)
{
    int frow = (j & (BB - 1)) * VV + (j >> 9);
    return (const float4*)&feat[(size_t)frow * DD + d];
}

// ---------------------------------------------------------------------------
// KA: merged node, two independent block roles (no intra-node dependency):
//  blocks 0..255   : K0 role — anchor (transposed feat) -> bf16 + exact norms
//                    (consumed only by K2, next node).
//  blocks 256..767 : K1 role — neighbor MFMA GEMM -> accT[b][i], with the
//                    anchor side read feat-direct (in-register cvt8 + shfl
//                    norms; validated R9, absmax 0). Grid-equivalent (128,4).
// ---------------------------------------------------------------------------
__global__ __launch_bounds__(256) void kA(
    const float* __restrict__ feat, const int* __restrict__ indices,
    const float* __restrict__ saved, const int* __restrict__ rks,
    unsigned* __restrict__ anchor_u, float* __restrict__ a2,
    float* __restrict__ accT)
{
    const int tid = threadIdx.x;
    const int lane = tid & 63;

    if (blockIdx.x < 256) {
        // ---------------- K0 role (R6 verbatim) ----------------
        const int row  = blockIdx.x * 4 + (tid >> 6);
        const int frow = (row & (BB - 1)) * VV + (row >> 9);
        float2 v = *(const float2*)&feat[(size_t)frow * DD + lane * 2];
        unsigned lo = (unsigned)(unsigned short)f2bf(v.x);
        unsigned hi = (unsigned)(unsigned short)f2bf(v.y);
        anchor_u[row * (DD / 2) + lane] = lo | (hi << 16);
        float sq = v.x * v.x + v.y * v.y;
        #pragma unroll
        for (int off = 32; off > 0; off >>= 1) sq += __shfl_xor(sq, off);
        if (lane == 0) a2[row] = sq;
        return;
    }

    // ---------------- K1 role (feat-direct B side) ----------------
    const int idx = blockIdx.x - 256;       // 0..511
    const int bx = idx & 127;
    const int by = idx >> 7;                // 0..3
    const int wid = tid >> 6;
    const int lr = lane & 15;
    const int lg = lane >> 4;
    const int wr = wid >> 1;
    const int wc = wid & 1;
    const int m0 = bx * 64 + wr * 32;       // neighbor row base

    // A side: gather 2 b-groups' saved rows (k = lr; k=15 masked in epilogue)
    int aidx[2];
    #pragma unroll
    for (int tm = 0; tm < 2; ++tm) {
        int b = (m0 >> 4) + tm;
        aidx[tm] = rks[(size_t)indices[b] * KMAX + lr];
    }
    bf16x8 af[2][4];
    float nnA[2] = {0.f, 0.f};
    #pragma unroll
    for (int tm = 0; tm < 2; ++tm)
        #pragma unroll
        for (int kc = 0; kc < 4; ++kc) {
            const float4* p = (const float4*)&saved[(size_t)aidx[tm] * DD + kc * 32 + lg * 8];
            af[tm][kc] = cvt8(p[0], p[1], nnA[tm]);
        }
    #pragma unroll
    for (int tm = 0; tm < 2; ++tm) {
        nnA[tm] += __shfl_xor(nnA[tm], 16);
        nnA[tm] += __shfl_xor(nnA[tm], 32);   // lane: full norm of row lr
    }
    float nnAr[2][4];
    #pragma unroll
    for (int tm = 0; tm < 2; ++tm)
        #pragma unroll
        for (int r = 0; r < 4; ++r)
            nnAr[tm][r] = __shfl(nnA[tm], lg * 4 + r);   // norm of C-row lg*4+r

    #pragma unroll
    for (int jt = 0; jt < 2; ++jt) {
        const int j0 = by * 256 + jt * 128 + wc * 64;
        f32x4 acc[2][4];
        #pragma unroll
        for (int a = 0; a < 2; ++a)
            #pragma unroll
            for (int b = 0; b < 4; ++b) acc[a][b] = (f32x4){0.f, 0.f, 0.f, 0.f};
        float nnB[4] = {0.f, 0.f, 0.f, 0.f};
        #pragma unroll
        for (int kc = 0; kc < 4; ++kc) {
            bf16x8 bf[4];
            #pragma unroll
            for (int tn = 0; tn < 4; ++tn) {
                const float4* p = feat_ptr(feat, j0 + tn * 16 + lr, kc * 32 + lg * 8);
                bf[tn] = cvt8(p[0], p[1], nnB[tn]);
            }
            #pragma unroll
            for (int tm = 0; tm < 2; ++tm)
                #pragma unroll
                for (int tn = 0; tn < 4; ++tn)
                    acc[tm][tn] = __builtin_amdgcn_mfma_f32_16x16x32_bf16(
                        af[tm][kc], bf[tn], acc[tm][tn], 0, 0, 0);
        }
        #pragma unroll
        for (int tn = 0; tn < 4; ++tn) {
            nnB[tn] += __shfl_xor(nnB[tn], 16);
            nnB[tn] += __shfl_xor(nnB[tn], 32);  // lane: full norm of col lr
        }
        #pragma unroll
        for (int tm = 0; tm < 2; ++tm) {
            const int b = (m0 >> 4) + tm;
            #pragma unroll
            for (int tn = 0; tn < 4; ++tn) {
                const float a2j = nnB[tn];
                float s = 0.f;
                #pragma unroll
                for (int r = 0; r < 4; ++r) {
                    float g = acc[tm][tn][r];
                    float sq = fmaxf(fmaf(-2.f, g, a2j + nnAr[tm][r]), 0.f);
                    float d = __builtin_amdgcn_sqrtf(sq);
                    float f = fmaf(__builtin_amdgcn_rcpf(1.f + d), INV_T, INV_T);
                    if (lg == 3 && r == 3) f = 0.f;  // k == 15 pad row
                    s += f;
                }
                s += __shfl_xor(s, 16);
                s += __shfl_xor(s, 32);              // sum the 16 k-rows
                if (lane < 16)
                    accT[(size_t)b * MM + j0 + tn * 16 + lane] = s * (1.0f / TOPK);
            }
        }
    }
}

// ---------------------------------------------------------------------------
// K2: S-tile MFMA + adc + ls + exp partial sums.  (R6 verbatim)
// Grid (64, 16): 16 i-rows x 64 j-cols per block; wave handles 16 cols.
// (No max subtraction: ls in [24.7, 49.5]; verified rounds 4-9, absmax 0.)
// ---------------------------------------------------------------------------
__global__ __launch_bounds__(256) void k2_exp(
    const short* __restrict__ anchor, const float* __restrict__ a2,
    const float* __restrict__ accT,
    float* __restrict__ part, float* __restrict__ lspos)
{
    __shared__ float pshare[4][16];
    const int tid = threadIdx.x;
    const int lane = tid & 63;
    const int wid = tid >> 6;
    const int lr = lane & 15;
    const int lg = lane >> 4;
    const int i0 = blockIdx.x * 16;
    const int jg = blockIdx.y;
    const int jcol = jg * 64 + wid * 16 + lr;

    f32x4 acc = (f32x4){0.f, 0.f, 0.f, 0.f};
    #pragma unroll
    for (int kc = 0; kc < 4; ++kc) {
        bf16x8 af = *(const bf16x8*)&anchor[(size_t)(i0 + lr) * DD + kc * 32 + lg * 8];
        bf16x8 bf = *(const bf16x8*)&anchor[(size_t)jcol * DD + kc * 32 + lg * 8];
        acc = __builtin_amdgcn_mfma_f32_16x16x32_bf16(af, bf, acc, 0, 0, 0);
    }
    const int ib4 = i0 + lg * 4;
    const float4 a2i4 = *(const float4*)&a2[ib4];
    const float a2iv[4] = {a2i4.x, a2i4.y, a2i4.z, a2i4.w};
    const float a2j = a2[jcol];
    const float4 aij4 = *(const float4*)&accT[(size_t)(jcol & (BB - 1)) * MM + ib4];
    const float aijv[4] = {aij4.x, aij4.y, aij4.z, aij4.w};

    float esum[4];
    #pragma unroll
    for (int r = 0; r < 4; ++r) {
        const int i = ib4 + r;
        float g = acc[r];
        float sq = fmaxf(fmaf(-2.f, g, a2iv[r] + a2j), 0.f);
        float d0 = __builtin_amdgcn_sqrtf(sq);
        float adc = fmaf(__builtin_amdgcn_rcpf(1.f + d0), INV_T, INV_T);
        float aji = accT[(size_t)(i & (BB - 1)) * MM + jcol];
        float ls = __builtin_amdgcn_sqrtf(aijv[r] * aijv[r] + aji * aji + adc * adc);
        esum[r] = (jcol == i) ? 0.f : __expf(ls);
        if (jcol == (i ^ BB)) lspos[i] = ls;            // the positive pair
    }
    #pragma unroll
    for (int r = 0; r < 4; ++r) {
        float e = esum[r];
        e += __shfl_xor(e, 1);
        e += __shfl_xor(e, 2);
        e += __shfl_xor(e, 4);
        e += __shfl_xor(e, 8);                          // sum 16 j's in wave
        if (lr == 0) pshare[wid][lg * 4 + r] = e;
    }
    __syncthreads();
    if (tid < 16)
        part[jg * MM + i0 + tid] =
            pshare[0][tid] + pshare[1][tid] + pshare[2][tid] + pshare[3][tid];
}

// ---------------------------------------------------------------------------
// K3: finish — loss per row + mean, single block.  (R6 verbatim)
// ---------------------------------------------------------------------------
__global__ __launch_bounds__(256) void k3_finish(
    const float* __restrict__ part, const float* __restrict__ lspos,
    float* __restrict__ out)
{
    __shared__ float red[4];
    const int tid = threadIdx.x;
    const int lane = tid & 63, w = tid >> 6;
    float lsum = 0.f;
    #pragma unroll
    for (int q = 0; q < 4; ++q) {
        const int i = tid + q * 256;
        float s = 0.f;
        #pragma unroll
        for (int jg = 0; jg < 16; ++jg) s += part[jg * MM + i];
        lsum += __logf(s) - lspos[i];
    }
    #pragma unroll
    for (int off = 32; off > 0; off >>= 1) lsum += __shfl_xor(lsum, off);
    if (lane == 0) red[w] = lsum;
    __syncthreads();
    if (tid == 0) out[0] = (red[0] + red[1] + red[2] + red[3]) * (1.0f / MM);
}

// ---------------------------------------------------------------------------
extern "C" void kernel_launch(void* const* d_in, const int* in_sizes, int n_in,
                              void* d_out, int out_size, void* d_ws, size_t ws_size,
                              hipStream_t stream)
{
    const float* feat    = (const float*)d_in[0];  // (512, 2, 128) f32
    const int*   indices = (const int*)  d_in[1];  // (512,) i32
    const float* saved   = (const float*)d_in[2];  // (100000, 128) f32
    const int*   rks     = (const int*)  d_in[3];  // (100000, 50) i32

    char* w = (char*)d_ws;
    short* anchor = (short*)(w + OFF_ANCH);
    float* a2     = (float*)(w + OFF_A2);
    float* accT   = (float*)(w + OFF_ACCT);
    float* part   = (float*)(w + OFF_PART);
    float* lspos  = (float*)(w + OFF_LSPOS);

    // Node 1: K0-role (blocks 0-255) + K1-role (blocks 256-767), independent
    kA<<<768, 256, 0, stream>>>(feat, indices, saved, rks,
                                (unsigned*)anchor, a2, accT);
    // Node 2: S-GEMM + adc + exp partials
    k2_exp<<<dim3(64, 16), 256, 0, stream>>>(anchor, a2, accT, part, lspos);
    // Node 3: loss + mean
    k3_finish<<<1, 256, 0, stream>>>(part, lspos, (float*)d_out);
}